// Round 21
// baseline (124.537 us; speedup 1.0000x reference)
//
#include <hip/hip_runtime.h>
#include <cstdint>
#include <cstddef>

#define D 128
#define ALPHA 0.2f

typedef _Float16 half8_t __attribute__((ext_vector_type(8)));
typedef _Float16 v2h __attribute__((ext_vector_type(2)));
typedef __attribute__((ext_vector_type(4))) float f32x4_t;

static __device__ __forceinline__ ushort f2h(float f) {
    _Float16 h = (_Float16)f;
    return *(ushort*)&h;
}

static __device__ __forceinline__ float dot2f(v2h x, v2h y, float c) {
#if __has_builtin(__builtin_amdgcn_fdot2)
    return __builtin_amdgcn_fdot2(x, y, c, false);
#else
    return fmaf((float)x[0], (float)y[0], fmaf((float)x[1], (float)y[1], c));
#endif
}

// ---------------------------------------------------------------------------
// Kernel P: fused prep — counts[i]=0, Wt (transposed fp16), Ah (fp16 a)
// ---------------------------------------------------------------------------
__global__ __launch_bounds__(256) void prep_kernel(const float* __restrict__ W,
                                                   const float* __restrict__ a,
                                                   ushort* __restrict__ Wt,
                                                   ushort* __restrict__ Ah,
                                                   int* __restrict__ counts, int N) {
    int idx = blockIdx.x * 256 + threadIdx.x;
    if (idx < 16384) {
        int k = idx >> 7;
        int n = idx & 127;
        Wt[n * 128 + k] = f2h(W[idx]);
    }
    if (idx < 128) Ah[idx] = f2h(a[idx]);
    if (idx < N) counts[idx] = 0;
}

// ---------------------------------------------------------------------------
// Fused kernel: blocks [0, gemmBlks) run the MFMA GEMM (Hf = fp16(A@W));
// blocks [gemmBlks, ...) run hist(+rank). Independent phases, resource-
// complementary (MFMA/LDS vs atomic-latency) — co-resident overlap.
// ---------------------------------------------------------------------------
__global__ __launch_bounds__(256) void gemm_hist_kernel(const float* __restrict__ A,
                                                        const ushort* __restrict__ Wt,
                                                        ushort* __restrict__ Hf,
                                                        const int* __restrict__ src,
                                                        int* __restrict__ counts,
                                                        int* __restrict__ rank,
                                                        int gemmBlks, int N, int E) {
    __shared__ ushort Alds[64][136];
    const int tid = threadIdx.x;

    if ((int)blockIdx.x >= gemmBlks) {
        // ---- histogram + rank ----
        int i = ((int)blockIdx.x - gemmBlks) * 256 + tid;
        if (i < E) rank[i] = atomicAdd(&counts[src[i]], 1);
        return;
    }

    // ---- GEMM ----
    const int r0 = blockIdx.x * 64;

#pragma unroll
    for (int it = 0; it < 8; ++it) {
        int idx = it * 256 + tid;          // 0..2047
        int r = idx >> 5;
        int c4 = (idx & 31) * 4;
        float4 v = make_float4(0.f, 0.f, 0.f, 0.f);
        if (r0 + r < N) v = *(const float4*)(A + (size_t)(r0 + r) * D + c4);
        ushort4 b;
        b.x = f2h(v.x); b.y = f2h(v.y); b.z = f2h(v.z); b.w = f2h(v.w);
        *(ushort4*)&Alds[r][c4] = b;
    }
    __syncthreads();

    const int lane = tid & 63;
    const int w = tid >> 6;
    const int wm = w >> 1;
    const int wn = w & 1;
    const int l15 = lane & 15;
    const int koff = (lane >> 4) * 8;

    f32x4_t acc[2][4];
#pragma unroll
    for (int mt = 0; mt < 2; ++mt)
#pragma unroll
        for (int nt = 0; nt < 4; ++nt) acc[mt][nt] = (f32x4_t){0.f, 0.f, 0.f, 0.f};

    const int arow = wm * 32 + l15;
#pragma unroll
    for (int kk = 0; kk < 4; ++kk) {
        half8_t am0 = *(const half8_t*)&Alds[arow][kk * 32 + koff];
        half8_t am1 = *(const half8_t*)&Alds[arow + 16][kk * 32 + koff];
        half8_t bn[4];
#pragma unroll
        for (int nt = 0; nt < 4; ++nt)
            bn[nt] = *(const half8_t*)(Wt + (size_t)(wn * 64 + nt * 16 + l15) * 128 + kk * 32 + koff);
#pragma unroll
        for (int nt = 0; nt < 4; ++nt) {
            acc[0][nt] = __builtin_amdgcn_mfma_f32_16x16x32_f16(am0, bn[nt], acc[0][nt], 0, 0, 0);
            acc[1][nt] = __builtin_amdgcn_mfma_f32_16x16x32_f16(am1, bn[nt], acc[1][nt], 0, 0, 0);
        }
    }

    const int crow = (lane >> 4) * 4;
#pragma unroll
    for (int mt = 0; mt < 2; ++mt)
#pragma unroll
        for (int nt = 0; nt < 4; ++nt)
#pragma unroll
            for (int r = 0; r < 4; ++r) {
                int row = r0 + wm * 32 + mt * 16 + crow + r;
                if (row < N)
                    Hf[(size_t)row * D + wn * 64 + nt * 16 + l15] = f2h(acc[mt][nt][r]);
            }
}

// ---------------------------------------------------------------------------
// Merged scan (single kernel): block b computes its offset by direct
// grid-stride sum of counts[0..b*256), then the in-block exclusive scan.
// (R13-correctness-proven; extra reads ~20MB L2 ≈ 1 µs, saves a dispatch.)
// ---------------------------------------------------------------------------
__global__ __launch_bounds__(256) void scan_kernel(const int* __restrict__ counts,
                                                   int* __restrict__ starts, int N) {
    __shared__ int bsum[4];
    __shared__ int wsum[4];
    int tid = threadIdx.x;
    int lane = tid & 63, w = tid >> 6;

    // phase 1: block offset = sum of counts[0 .. blockIdx.x*256)
    int lim = blockIdx.x << 8;
    int x0 = 0;
    for (int i = tid; i < lim; i += 256) x0 += counts[i];
#pragma unroll
    for (int off = 32; off > 0; off >>= 1) x0 += __shfl_down(x0, off);
    if (lane == 0) bsum[w] = x0;
    __syncthreads();
    int blkoff = bsum[0] + bsum[1] + bsum[2] + bsum[3];

    // phase 2: in-block exclusive scan
    int i = (blockIdx.x << 8) + tid;
    int c = (i < N) ? counts[i] : 0;
    int x = c;
#pragma unroll
    for (int off = 1; off < 64; off <<= 1) {
        int y = __shfl_up(x, off);
        if (lane >= off) x += y;
    }
    if (lane == 63) wsum[w] = x;
    __syncthreads();
    int woff = blkoff;
    for (int j = 0; j < w; ++j) woff += wsum[j];
    int pre = woff + x - c;
    if (i < N) {
        starts[i] = pre;
        if (i == N - 1) starts[N] = pre + c;
    }
}

// edge list stored as BYTE OFFSETS into Hf (dst << 8)
__global__ __launch_bounds__(256) void scatter_kernel(const int* __restrict__ src,
                                                      const int* __restrict__ dst,
                                                      const int* __restrict__ rank,
                                                      const int* __restrict__ starts,
                                                      int* __restrict__ dst_off, int E) {
    int i = blockIdx.x * 256 + threadIdx.x;
    if (i >= E) return;
    int pos = starts[src[i]] + rank[i];
    dst_off[pos] = dst[i] << 8;   // byte offset of row in Hf (128 * 2B)
}

// ---------------------------------------------------------------------------
// Node kernel: 1 block = 1 wave = 1 node (node = blockIdx.x wave-uniform ->
// scalar edge loads, SGPR gather base). Edge list = precomputed byte offsets.
// fp16 packed QK; butterfly multi-reduce; readlane e-broadcast; deferred
// rowsum fold.  [R18-proven]
// ---------------------------------------------------------------------------
template <bool FULL>
__device__ __forceinline__ void process_chunk(const char* __restrict__ Hb,
                                              const int* __restrict__ dst_off,
                                              int base, int cnt, int l,
                                              v2h hs2, v2h av2, v2h alpha2,
                                              float& acc0, float& acc1, float& rsp) {
    uint fu[16];
#pragma unroll
    for (int j = 0; j < 16; ++j) {
        int idx = FULL ? (base + j) : (base + (j < cnt ? j : 0));
        int doff = dst_off[idx];                         // wave-uniform -> s_load
        const char* rp = Hb + (uint)doff;                // SGPR base + 64-bit add only
        fu[j] = *(const uint*)(rp + (l << 2));
    }
    float p[16];
#pragma unroll
    for (int j = 0; j < 16; ++j) {
        v2h hv = *(v2h*)&fu[j];
        v2h s = hs2 + hv;                                    // v_pk_add_f16
        s = __builtin_elementwise_max(s, s * alpha2);        // v_pk_mul + v_pk_max
        float pj = dot2f(s, av2, 0.0f);                      // v_dot2_f32_f16
        p[j] = (FULL || j < cnt) ? pj : -1e30f;
    }
    // butterfly multi-reduce: 16 values over 64 lanes
    {
        bool hi = l & 1;
#pragma unroll
        for (int i = 0; i < 8; ++i) {
            float send = hi ? p[i] : p[i + 8];
            float recv = __shfl_xor(send, 1);
            p[i] = (hi ? p[i + 8] : p[i]) + recv;
        }
        hi = l & 2;
#pragma unroll
        for (int i = 0; i < 4; ++i) {
            float send = hi ? p[i] : p[i + 4];
            float recv = __shfl_xor(send, 2);
            p[i] = (hi ? p[i + 4] : p[i]) + recv;
        }
        hi = l & 4;
#pragma unroll
        for (int i = 0; i < 2; ++i) {
            float send = hi ? p[i] : p[i + 2];
            float recv = __shfl_xor(send, 4);
            p[i] = (hi ? p[i + 2] : p[i]) + recv;
        }
        hi = l & 8;
        {
            float send = hi ? p[0] : p[1];
            float recv = __shfl_xor(send, 8);
            p[0] = (hi ? p[1] : p[0]) + recv;
        }
        p[0] += __shfl_xor(p[0], 16);
        p[0] += __shfl_xor(p[0], 32);
    }
    float e = __expf(p[0]);      // lane l: e of edge brev4(l&15), replicated per 16 lanes
    rsp += e;                    // deferred rowsum fold

    const int brev[16] = {0, 8, 4, 12, 2, 10, 6, 14, 1, 9, 5, 13, 3, 11, 7, 15};
#pragma unroll
    for (int j = 0; j < 16; ++j) {
        float ej = __uint_as_float(
            (uint)__builtin_amdgcn_readlane((int)__float_as_uint(e), brev[j]));
        v2h hv = *(v2h*)&fu[j];
        acc0 = fmaf((float)hv[0], ej, acc0);   // v_fma_mix
        acc1 = fmaf((float)hv[1], ej, acc1);   // v_fma_mix
    }
}

__global__ __launch_bounds__(64) void node_kernel(const ushort* __restrict__ Hf,
                                                  const int* __restrict__ starts,
                                                  const int* __restrict__ dst_off,
                                                  const ushort* __restrict__ Ah,
                                                  float* __restrict__ out, int N) {
    const int node = blockIdx.x;   // wave-uniform
    const int l = threadIdx.x;     // 0..63

    const int beg = starts[node];
    const int end = starts[node + 1];

    uint hu = *(const uint*)(Hf + ((size_t)node << 7) + (l << 1));
    v2h hs2 = *(v2h*)&hu;
    uint au = *(const uint*)(Ah + (l << 1));
    v2h av2 = *(v2h*)&au;
    const v2h alpha2 = {(_Float16)ALPHA, (_Float16)ALPHA};

    const char* Hb = (const char*)Hf;

    float acc0 = 0.f, acc1 = 0.f, rsp = 0.f;

    int base = beg;
    for (; base + 16 <= end; base += 16)
        process_chunk<true>(Hb, dst_off, base, 16, l, hs2, av2, alpha2, acc0, acc1, rsp);
    if (base < end)
        process_chunk<false>(Hb, dst_off, base, end - base, l, hs2, av2, alpha2, acc0, acc1, rsp);

    // rowsum: e replicated across 16-lane groups; fold within 16
    float rs = rsp;
    rs += __shfl_xor(rs, 1);
    rs += __shfl_xor(rs, 2);
    rs += __shfl_xor(rs, 4);
    rs += __shfl_xor(rs, 8);

    float inv = 1.0f / rs;
    float2 o;
    o.x = fmaxf(acc0 * inv, 0.f);
    o.y = fmaxf(acc1 * inv, 0.f);
    *(float2*)(out + ((size_t)node << 7) + (l << 1)) = o;
}

extern "C" void kernel_launch(void* const* d_in, const int* in_sizes, int n_in,
                              void* d_out, int out_size, void* d_ws, size_t ws_size,
                              hipStream_t stream) {
    const float* inputs = (const float*)d_in[0];
    const int* edge = (const int*)d_in[1];
    const float* W = (const float*)d_in[2];
    const float* a = (const float*)d_in[3];
    float* out = (float*)d_out;

    const int N = in_sizes[0] / D;   // 50000
    const int E = in_sizes[1] / 2;   // 800000

    const int* src = edge;
    const int* dst = edge + E;

    // ws layout
    ushort* wt = (ushort*)d_ws;                      // [16384] fp16
    ushort* ah = wt + 16384;                         // [128]  fp16
    ushort* hf = ah + 128;                           // [N*128] fp16
    int* counts = (int*)(hf + (size_t)N * D);        // [N]
    int* starts = counts + N;                        // [N+1]
    int* rank = starts + N + 1;                      // [E]
    int* dst_off = rank + E;                         // [E] byte offsets

    const int nblk = (N + 255) / 256;                // 196
    const int eblk = (E + 255) / 256;                // 3125
    const int gemmBlks = (N + 63) / 64;              // 782

    prep_kernel<<<nblk, 256, 0, stream>>>(W, a, wt, ah, counts, N);
    gemm_hist_kernel<<<gemmBlks + eblk, 256, 0, stream>>>(inputs, wt, hf, src, counts,
                                                          rank, gemmBlks, N, E);
    scan_kernel<<<nblk, 256, 0, stream>>>(counts, starts, N);
    scatter_kernel<<<eblk, 256, 0, stream>>>(src, dst, rank, starts, dst_off, E);
    node_kernel<<<N, 64, 0, stream>>>(hf, starts, dst_off, ah, out, N);
}

// Round 22
// 100.568 us; speedup vs baseline: 1.2383x; 1.2383x over previous
//
#include <hip/hip_runtime.h>
#include <cstdint>
#include <cstddef>

#define D 128
#define ALPHA 0.2f

typedef _Float16 half8_t __attribute__((ext_vector_type(8)));
typedef _Float16 v2h __attribute__((ext_vector_type(2)));
typedef __attribute__((ext_vector_type(4))) float f32x4_t;

static __device__ __forceinline__ ushort f2h(float f) {
    _Float16 h = (_Float16)f;
    return *(ushort*)&h;
}

static __device__ __forceinline__ float dot2f(v2h x, v2h y, float c) {
#if __has_builtin(__builtin_amdgcn_fdot2)
    return __builtin_amdgcn_fdot2(x, y, c, false);
#else
    return fmaf((float)x[0], (float)y[0], fmaf((float)x[1], (float)y[1], c));
#endif
}

// ---------------------------------------------------------------------------
// Kernel P: fused prep — counts[i]=0, Wt (transposed fp16), Ah (fp16 a)
// ---------------------------------------------------------------------------
__global__ __launch_bounds__(256) void prep_kernel(const float* __restrict__ W,
                                                   const float* __restrict__ a,
                                                   ushort* __restrict__ Wt,
                                                   ushort* __restrict__ Ah,
                                                   int* __restrict__ counts, int N) {
    int idx = blockIdx.x * 256 + threadIdx.x;
    if (idx < 16384) {
        int k = idx >> 7;
        int n = idx & 127;
        Wt[n * 128 + k] = f2h(W[idx]);
    }
    if (idx < 128) Ah[idx] = f2h(a[idx]);
    if (idx < N) counts[idx] = 0;
}

// ---------------------------------------------------------------------------
// Fused kernel: blocks [0, gemmBlks) run the MFMA GEMM (Hf = fp16(A@W));
// blocks [gemmBlks, ...) run hist(+rank). Independent phases, resource-
// complementary (MFMA/LDS vs atomic-latency) — co-resident overlap.
// ---------------------------------------------------------------------------
__global__ __launch_bounds__(256) void gemm_hist_kernel(const float* __restrict__ A,
                                                        const ushort* __restrict__ Wt,
                                                        ushort* __restrict__ Hf,
                                                        const int* __restrict__ src,
                                                        int* __restrict__ counts,
                                                        int* __restrict__ rank,
                                                        int gemmBlks, int N, int E) {
    __shared__ ushort Alds[64][136];
    const int tid = threadIdx.x;

    if ((int)blockIdx.x >= gemmBlks) {
        // ---- histogram + rank ----
        int i = ((int)blockIdx.x - gemmBlks) * 256 + tid;
        if (i < E) rank[i] = atomicAdd(&counts[src[i]], 1);
        return;
    }

    // ---- GEMM ----
    const int r0 = blockIdx.x * 64;

#pragma unroll
    for (int it = 0; it < 8; ++it) {
        int idx = it * 256 + tid;          // 0..2047
        int r = idx >> 5;
        int c4 = (idx & 31) * 4;
        float4 v = make_float4(0.f, 0.f, 0.f, 0.f);
        if (r0 + r < N) v = *(const float4*)(A + (size_t)(r0 + r) * D + c4);
        ushort4 b;
        b.x = f2h(v.x); b.y = f2h(v.y); b.z = f2h(v.z); b.w = f2h(v.w);
        *(ushort4*)&Alds[r][c4] = b;
    }
    __syncthreads();

    const int lane = tid & 63;
    const int w = tid >> 6;
    const int wm = w >> 1;
    const int wn = w & 1;
    const int l15 = lane & 15;
    const int koff = (lane >> 4) * 8;

    f32x4_t acc[2][4];
#pragma unroll
    for (int mt = 0; mt < 2; ++mt)
#pragma unroll
        for (int nt = 0; nt < 4; ++nt) acc[mt][nt] = (f32x4_t){0.f, 0.f, 0.f, 0.f};

    const int arow = wm * 32 + l15;
#pragma unroll
    for (int kk = 0; kk < 4; ++kk) {
        half8_t am0 = *(const half8_t*)&Alds[arow][kk * 32 + koff];
        half8_t am1 = *(const half8_t*)&Alds[arow + 16][kk * 32 + koff];
        half8_t bn[4];
#pragma unroll
        for (int nt = 0; nt < 4; ++nt)
            bn[nt] = *(const half8_t*)(Wt + (size_t)(wn * 64 + nt * 16 + l15) * 128 + kk * 32 + koff);
#pragma unroll
        for (int nt = 0; nt < 4; ++nt) {
            acc[0][nt] = __builtin_amdgcn_mfma_f32_16x16x32_f16(am0, bn[nt], acc[0][nt], 0, 0, 0);
            acc[1][nt] = __builtin_amdgcn_mfma_f32_16x16x32_f16(am1, bn[nt], acc[1][nt], 0, 0, 0);
        }
    }

    const int crow = (lane >> 4) * 4;
#pragma unroll
    for (int mt = 0; mt < 2; ++mt)
#pragma unroll
        for (int nt = 0; nt < 4; ++nt)
#pragma unroll
            for (int r = 0; r < 4; ++r) {
                int row = r0 + wm * 32 + mt * 16 + crow + r;
                if (row < N)
                    Hf[(size_t)row * D + wn * 64 + nt * 16 + l15] = f2h(acc[mt][nt][r]);
            }
}

// ---------------------------------------------------------------------------
// Scan: partial sums -> final (block offset from blocksum inline)
// ---------------------------------------------------------------------------
__global__ __launch_bounds__(256) void scan_partial_kernel(const int* __restrict__ counts,
                                                           int* __restrict__ blocksum, int N) {
    __shared__ int wsum[4];
    int tid = threadIdx.x;
    int i = blockIdx.x * 256 + tid;
    int x = (i < N) ? counts[i] : 0;
#pragma unroll
    for (int off = 32; off > 0; off >>= 1) x += __shfl_down(x, off);
    if ((tid & 63) == 0) wsum[tid >> 6] = x;
    __syncthreads();
    if (tid == 0) blocksum[blockIdx.x] = wsum[0] + wsum[1] + wsum[2] + wsum[3];
}

__global__ __launch_bounds__(256) void scan_final_kernel(const int* __restrict__ counts,
                                                         const int* __restrict__ blocksum,
                                                         int* __restrict__ starts,
                                                         int nblk, int N) {
    __shared__ int bsum[4];
    __shared__ int wsum[4];
    int tid = threadIdx.x;
    int lane = tid & 63, w = tid >> 6;

    int x0 = (tid < nblk && tid < (int)blockIdx.x) ? blocksum[tid] : 0;
#pragma unroll
    for (int off = 32; off > 0; off >>= 1) x0 += __shfl_down(x0, off);
    if (lane == 0) bsum[w] = x0;
    __syncthreads();
    int blkoff = bsum[0] + bsum[1] + bsum[2] + bsum[3];

    int i = blockIdx.x * 256 + tid;
    int c = (i < N) ? counts[i] : 0;
    int x = c;
#pragma unroll
    for (int off = 1; off < 64; off <<= 1) {
        int y = __shfl_up(x, off);
        if (lane >= off) x += y;
    }
    if (lane == 63) wsum[w] = x;
    __syncthreads();
    int woff = blkoff;
    for (int j = 0; j < w; ++j) woff += wsum[j];
    int pre = woff + x - c;
    if (i < N) {
        starts[i] = pre;
        if (i == N - 1) starts[N] = pre + c;
    }
}

// edge list stored as BYTE OFFSETS into Hf (dst << 8)
__global__ __launch_bounds__(256) void scatter_kernel(const int* __restrict__ src,
                                                      const int* __restrict__ dst,
                                                      const int* __restrict__ rank,
                                                      const int* __restrict__ starts,
                                                      int* __restrict__ dst_off, int E) {
    int i = blockIdx.x * 256 + threadIdx.x;
    if (i >= E) return;
    int pos = starts[src[i]] + rank[i];
    dst_off[pos] = dst[i] << 8;   // byte offset of row in Hf (128 * 2B)
}

// ---------------------------------------------------------------------------
// Node kernel: 1 block = 1 wave = 1 node (node = blockIdx.x wave-uniform ->
// scalar edge loads, SGPR gather base). Edge list = precomputed byte offsets.
// fp16 packed QK; butterfly multi-reduce; readlane e-broadcast; deferred
// rowsum fold.  [R18-proven]
// ---------------------------------------------------------------------------
template <bool FULL>
__device__ __forceinline__ void process_chunk(const char* __restrict__ Hb,
                                              const int* __restrict__ dst_off,
                                              int base, int cnt, int l,
                                              v2h hs2, v2h av2, v2h alpha2,
                                              float& acc0, float& acc1, float& rsp) {
    uint fu[16];
#pragma unroll
    for (int j = 0; j < 16; ++j) {
        int idx = FULL ? (base + j) : (base + (j < cnt ? j : 0));
        int doff = dst_off[idx];                         // wave-uniform -> s_load
        const char* rp = Hb + (uint)doff;                // SGPR base + 64-bit add only
        fu[j] = *(const uint*)(rp + (l << 2));
    }
    float p[16];
#pragma unroll
    for (int j = 0; j < 16; ++j) {
        v2h hv = *(v2h*)&fu[j];
        v2h s = hs2 + hv;                                    // v_pk_add_f16
        s = __builtin_elementwise_max(s, s * alpha2);        // v_pk_mul + v_pk_max
        float pj = dot2f(s, av2, 0.0f);                      // v_dot2_f32_f16
        p[j] = (FULL || j < cnt) ? pj : -1e30f;
    }
    // butterfly multi-reduce: 16 values over 64 lanes
    {
        bool hi = l & 1;
#pragma unroll
        for (int i = 0; i < 8; ++i) {
            float send = hi ? p[i] : p[i + 8];
            float recv = __shfl_xor(send, 1);
            p[i] = (hi ? p[i + 8] : p[i]) + recv;
        }
        hi = l & 2;
#pragma unroll
        for (int i = 0; i < 4; ++i) {
            float send = hi ? p[i] : p[i + 4];
            float recv = __shfl_xor(send, 2);
            p[i] = (hi ? p[i + 4] : p[i]) + recv;
        }
        hi = l & 4;
#pragma unroll
        for (int i = 0; i < 2; ++i) {
            float send = hi ? p[i] : p[i + 2];
            float recv = __shfl_xor(send, 4);
            p[i] = (hi ? p[i + 2] : p[i]) + recv;
        }
        hi = l & 8;
        {
            float send = hi ? p[0] : p[1];
            float recv = __shfl_xor(send, 8);
            p[0] = (hi ? p[1] : p[0]) + recv;
        }
        p[0] += __shfl_xor(p[0], 16);
        p[0] += __shfl_xor(p[0], 32);
    }
    float e = __expf(p[0]);      // lane l: e of edge brev4(l&15), replicated per 16 lanes
    rsp += e;                    // deferred rowsum fold

    const int brev[16] = {0, 8, 4, 12, 2, 10, 6, 14, 1, 9, 5, 13, 3, 11, 7, 15};
#pragma unroll
    for (int j = 0; j < 16; ++j) {
        float ej = __uint_as_float(
            (uint)__builtin_amdgcn_readlane((int)__float_as_uint(e), brev[j]));
        v2h hv = *(v2h*)&fu[j];
        acc0 = fmaf((float)hv[0], ej, acc0);   // v_fma_mix
        acc1 = fmaf((float)hv[1], ej, acc1);   // v_fma_mix
    }
}

__global__ __launch_bounds__(64) void node_kernel(const ushort* __restrict__ Hf,
                                                  const int* __restrict__ starts,
                                                  const int* __restrict__ dst_off,
                                                  const ushort* __restrict__ Ah,
                                                  float* __restrict__ out, int N) {
    const int node = blockIdx.x;   // wave-uniform
    const int l = threadIdx.x;     // 0..63

    const int beg = starts[node];
    const int end = starts[node + 1];

    uint hu = *(const uint*)(Hf + ((size_t)node << 7) + (l << 1));
    v2h hs2 = *(v2h*)&hu;
    uint au = *(const uint*)(Ah + (l << 1));
    v2h av2 = *(v2h*)&au;
    const v2h alpha2 = {(_Float16)ALPHA, (_Float16)ALPHA};

    const char* Hb = (const char*)Hf;

    float acc0 = 0.f, acc1 = 0.f, rsp = 0.f;

    int base = beg;
    for (; base + 16 <= end; base += 16)
        process_chunk<true>(Hb, dst_off, base, 16, l, hs2, av2, alpha2, acc0, acc1, rsp);
    if (base < end)
        process_chunk<false>(Hb, dst_off, base, end - base, l, hs2, av2, alpha2, acc0, acc1, rsp);

    // rowsum: e replicated across 16-lane groups; fold within 16
    float rs = rsp;
    rs += __shfl_xor(rs, 1);
    rs += __shfl_xor(rs, 2);
    rs += __shfl_xor(rs, 4);
    rs += __shfl_xor(rs, 8);

    float inv = 1.0f / rs;
    float2 o;
    o.x = fmaxf(acc0 * inv, 0.f);
    o.y = fmaxf(acc1 * inv, 0.f);
    *(float2*)(out + ((size_t)node << 7) + (l << 1)) = o;
}

extern "C" void kernel_launch(void* const* d_in, const int* in_sizes, int n_in,
                              void* d_out, int out_size, void* d_ws, size_t ws_size,
                              hipStream_t stream) {
    const float* inputs = (const float*)d_in[0];
    const int* edge = (const int*)d_in[1];
    const float* W = (const float*)d_in[2];
    const float* a = (const float*)d_in[3];
    float* out = (float*)d_out;

    const int N = in_sizes[0] / D;   // 50000
    const int E = in_sizes[1] / 2;   // 800000

    const int* src = edge;
    const int* dst = edge + E;

    // ws layout
    ushort* wt = (ushort*)d_ws;                      // [16384] fp16
    ushort* ah = wt + 16384;                         // [128]  fp16
    ushort* hf = ah + 128;                           // [N*128] fp16
    int* counts = (int*)(hf + (size_t)N * D);        // [N]
    int* starts = counts + N;                        // [N+1]
    int* blocksum = starts + N + 1;                  // [256]
    int* rank = blocksum + 256;                      // [E]
    int* dst_off = rank + E;                         // [E] byte offsets

    const int nblk = (N + 255) / 256;                // 196
    const int eblk = (E + 255) / 256;                // 3125
    const int gemmBlks = (N + 63) / 64;              // 782

    prep_kernel<<<nblk, 256, 0, stream>>>(W, a, wt, ah, counts, N);
    gemm_hist_kernel<<<gemmBlks + eblk, 256, 0, stream>>>(inputs, wt, hf, src, counts,
                                                          rank, gemmBlks, N, E);
    scan_partial_kernel<<<nblk, 256, 0, stream>>>(counts, blocksum, N);
    scan_final_kernel<<<nblk, 256, 0, stream>>>(counts, blocksum, starts, nblk, N);
    scatter_kernel<<<eblk, 256, 0, stream>>>(src, dst, rank, starts, dst_off, E);
    node_kernel<<<N, 64, 0, stream>>>(hf, starts, dst_off, ah, out, N);
}